// Round 1
// 594.835 us; speedup vs baseline: 1.1772x; 1.1772x over previous
//
#include <hip/hip_runtime.h>
#include <hip/hip_bf16.h>
#include <math.h>

typedef __attribute__((ext_vector_type(8))) short bfrag8;
typedef __attribute__((ext_vector_type(4))) float ffrag4;

// ---------- helpers ----------
__device__ inline float bf2f(unsigned short h) { return __uint_as_float(((unsigned)h) << 16); }
__device__ inline unsigned short f2bf(float f) {
    unsigned u = __float_as_uint(f);
    unsigned r = (u + 0x7FFFu + ((u >> 16) & 1u)) >> 16;
    return (unsigned short)r;
}
__device__ inline float wred(float v) {
    v += __shfl_xor(v, 1, 64);
    v += __shfl_xor(v, 2, 64);
    v += __shfl_xor(v, 4, 64);
    v += __shfl_xor(v, 8, 64);
    v += __shfl_xor(v, 16, 64);
    v += __shfl_xor(v, 32, 64);
    return v;
}
__device__ inline float wredmax(float v) {
    v = fmaxf(v, __shfl_xor(v, 1, 64));
    v = fmaxf(v, __shfl_xor(v, 2, 64));
    v = fmaxf(v, __shfl_xor(v, 4, 64));
    v = fmaxf(v, __shfl_xor(v, 8, 64));
    v = fmaxf(v, __shfl_xor(v, 16, 64));
    v = fmaxf(v, __shfl_xor(v, 32, 64));
    return v;
}
__device__ inline float bsum(float v, float* red) {
    v = wred(v);
    if ((threadIdx.x & 63) == 0) red[threadIdx.x >> 6] = v;
    __syncthreads();
    float r = red[0] + red[1] + red[2] + red[3];
    __syncthreads();
    return r;
}

#define ACLIP (1.0f - 1e-7f)

// ---------- dtype detection ----------
__global__ void k_detect(const unsigned short* __restrict__ hyper, int* __restrict__ flag) {
    __shared__ int total;
    int t = threadIdx.x;
    if (t == 0) total = 0;
    __syncthreads();
    int cnt = 0;
    for (int i = t * 8; i < t * 8 + 8; i++) {
        if ((i & 1) == 0) {
            unsigned e = ((unsigned)hyper[i] >> 7) & 0xFF;
            if (e >= 0xC0) cnt++;
        }
    }
    atomicAdd(&total, cnt);
    __syncthreads();
    if (t == 0) *flag = (total >= 32) ? 1 : 0;   // 1 = inputs are float32
}

// ---------- fused small-param conversion ----------
__device__ inline float ldin(const void* s, int i, int isf32) {
    return isf32 ? ((const float*)s)[i] : bf2f(((const unsigned short*)s)[i]);
}
__global__ void k_params(const void* __restrict__ w_src, const void* __restrict__ w_dst,
                         const void* __restrict__ b_src, const void* __restrict__ b_dst,
                         const void* __restrict__ attn, const void* __restrict__ time_w,
                         const void* __restrict__ time_b,
                         unsigned short* __restrict__ whs, unsigned short* __restrict__ wls,
                         unsigned short* __restrict__ whd, unsigned short* __restrict__ wld,
                         float* __restrict__ bsrc, float* __restrict__ bdst,
                         float* __restrict__ pattn, float* __restrict__ tw,
                         float* __restrict__ tb, const int* __restrict__ flag, int nw) {
    int i = blockIdx.x * blockDim.x + threadIdx.x;
    int isf32 = *flag;
    if (i < nw) {
        float x = ldin(w_src, i, isf32);
        unsigned short h = f2bf(x);
        whs[i] = h; wls[i] = f2bf(x - bf2f(h));
        float y = ldin(w_dst, i, isf32);
        unsigned short g = f2bf(y);
        whd[i] = g; wld[i] = f2bf(y - bf2f(g));
    }
    if (i < 256) {
        bsrc[i] = ldin(b_src, i, isf32);
        bdst[i] = ldin(b_dst, i, isf32);
        pattn[i] = ldin(attn, i, isf32);
    }
    if (i < 128) {
        tw[i] = ldin(time_w, i, isf32);
        tb[i] = ldin(time_b, i, isf32);
    }
}
__global__ void k_fill(unsigned* __restrict__ p, unsigned v, int n) {
    int i = blockIdx.x * blockDim.x + threadIdx.x;
    if (i < n) p[i] = v;
}

// ---------- CSR build ----------
__global__ void k_hist(const int* __restrict__ dst_idx, int* __restrict__ deg, int n_edge) {
    int i = blockIdx.x * blockDim.x + threadIdx.x;
    if (i < n_edge) atomicAdd(deg + dst_idx[i], 1);
}
__global__ __launch_bounds__(1024) void k_scan(const int* __restrict__ deg,
                                               int* __restrict__ rowptr,
                                               int* __restrict__ cursor, int n) {
    __shared__ int part[1024];
    int t = threadIdx.x;
    int chunk = (n + 1023) >> 10;
    int lo = t * chunk, hi = min(lo + chunk, n);
    int s = 0;
    for (int i = lo; i < hi; i++) s += deg[i];
    part[t] = s;
    __syncthreads();
    for (int dd = 1; dd < 1024; dd <<= 1) {
        int v = (t >= dd) ? part[t - dd] : 0;
        __syncthreads();
        part[t] += v;
        __syncthreads();
    }
    int base = (t == 0) ? 0 : part[t - 1];
    for (int i = lo; i < hi; i++) {
        rowptr[i] = base; cursor[i] = base;
        base += deg[i];
    }
    if (t == 0) rowptr[n] = part[1023];
}
__global__ void k_scatter_edges(const int* __restrict__ src_idx, const int* __restrict__ dst_idx,
                                int* __restrict__ cursor, int* __restrict__ es, int n_edge) {
    int i = blockIdx.x * blockDim.x + threadIdx.x;
    if (i >= n_edge) return;
    int slot = atomicAdd(cursor + dst_idx[i], 1);
    es[slot] = src_idx[i];
}

// ---------- stage 1: per-node prologue (wave per node) -> Ah/Al bf16 split ----------
__global__ void k_node_prep(const void* __restrict__ hyper_v,
                            const void* __restrict__ dt_v,
                            const float* __restrict__ tw, const float* __restrict__ tb,
                            unsigned short* __restrict__ Ah, unsigned short* __restrict__ Al,
                            float* __restrict__ tnode,
                            const int* __restrict__ flag, int n_dst, int n_total) {
    int wid  = (blockIdx.x * blockDim.x + threadIdx.x) >> 6;
    int lane = threadIdx.x & 63;
    if (wid >= n_total) return;
    int isf32 = *flag;
    float tval = 0.0f;
    if (wid >= n_dst) {
        int e = wid - n_dst;
        tval = isf32 ? ((const float*)dt_v)[e] : bf2f(((const unsigned short*)dt_v)[e]);
    }
    int j0 = lane * 2;
    float tf0 = cosf(tval * tw[j0]     + tb[j0]);
    float tf1 = cosf(tval * tw[j0 + 1] + tb[j0 + 1]);
    float h0, h1;
    if (isf32) {
        const float* hp = (const float*)hyper_v + (size_t)wid * 128 + j0;
        h0 = hp[0]; h1 = hp[1];
    } else {
        const unsigned short* hp = (const unsigned short*)hyper_v + (size_t)wid * 128 + j0;
        h0 = bf2f(hp[0]); h1 = bf2f(hp[1]);
    }
    float ptf2 = wred(tf0 * tf0 + tf1 * tf1);
    float ph2  = wred(h0 * h0 + h1 * h1);
    float pht  = wred(h0 * tf0 + h1 * tf1);
    float ntf = sqrtf(fmaxf(ptf2, 1e-30f));
    float maxn = 1.0f - 0.004f;
    float sc = (ntf > maxn) ? (maxn / ntf) : 1.0f;
    float y2 = sc * sc * ptf2, xy = sc * pht, x2 = ph2;
    float A = 1.0f + 2.0f * xy + y2;
    float B = 1.0f - x2;
    float iden = 1.0f / fmaxf(1.0f + 2.0f * xy + x2 * y2, 1e-15f);
    float s0 = (A * h0 + B * sc * tf0) * iden;
    float s1 = (A * h1 + B * sc * tf1) * iden;
    unsigned short h0s = f2bf(s0), h1s = f2bf(s1);
    unsigned short l0s = f2bf(s0 - bf2f(h0s)), l1s = f2bf(s1 - bf2f(h1s));
    *(ushort2*)(Ah + (size_t)wid * 128 + j0) = make_ushort2(h0s, h1s);
    *(ushort2*)(Al + (size_t)wid * 128 + j0) = make_ushort2(l0s, l1s);
    float ps2 = wred(s0 * s0 + s1 * s1);
    float xn = sqrtf(fmaxf(ps2, 1e-30f));
    float g = atanhf(fminf(xn, ACLIP)) / xn;
    if (lane == 0) tnode[wid] = g;
}

// ---------- stage 2+3 fused: split-bf16 MFMA GEMM (32 rows/wave) + epilogue ----------
// NEW: B (Wh+Wl) staged in LDS once per 512-thread block (8 waves, 256 rows).
// Padded pitch 136 (272 B rows) -> row-stride reads hit 8 distinct bank groups
// (2-way aliasing = free). Removes 128 L2 round-trips per wave from the loop.
#define WPITCH 136
#define GEMM_LDS (256 * WPITCH * 2 * 2)   // 139264 B -> 1 block/CU
__global__ __launch_bounds__(512, 2) void k_gemm_ep(
        const unsigned short* __restrict__ Ah, const unsigned short* __restrict__ Al,
        const unsigned short* __restrict__ Wh, const unsigned short* __restrict__ Wl,
        const float* __restrict__ bvec, const float* __restrict__ attn,
        const float* __restrict__ tnode,
        float* __restrict__ feat, float* __restrict__ x2a, float* __restrict__ ca,
        float* __restrict__ satt, int base, int M) {
    extern __shared__ unsigned short smem[];
    unsigned short* Bhs = smem;                    // [256][WPITCH]
    unsigned short* Bls = smem + 256 * WPITCH;

    int t = threadIdx.x;
    // cooperative staging: 256x128 bf16 x2, 8 bf16 per vec op
    for (int v = t; v < 4096; v += 512) {
        int e = v << 3;
        int row = e >> 7, col = e & 127;
        *(bfrag8*)(Bhs + row * WPITCH + col) = *(const bfrag8*)(Wh + e);
        *(bfrag8*)(Bls + row * WPITCH + col) = *(const bfrag8*)(Wl + e);
    }
    __syncthreads();

    int w = t >> 6, lane = t & 63;
    int m16 = lane & 15, kg = lane >> 4;
    int rowbase = (blockIdx.x * 8 + w) * 32;
    int ar0 = min(rowbase + m16, M - 1);
    int ar1 = min(rowbase + 16 + m16, M - 1);
    const unsigned short* A0h = Ah + (size_t)ar0 * 128;
    const unsigned short* A0l = Al + (size_t)ar0 * 128;
    const unsigned short* A1h = Ah + (size_t)ar1 * 128;
    const unsigned short* A1l = Al + (size_t)ar1 * 128;

    ffrag4 acc[2][16];
#pragma unroll
    for (int p = 0; p < 2; p++)
#pragma unroll
        for (int ct = 0; ct < 16; ct++) acc[p][ct] = (ffrag4){0.0f, 0.0f, 0.0f, 0.0f};

    int kA = kg * 8;
    bfrag8 ah0 = *(const bfrag8*)(A0h + kA);
    bfrag8 al0 = *(const bfrag8*)(A0l + kA);
    bfrag8 ah1 = *(const bfrag8*)(A1h + kA);
    bfrag8 al1 = *(const bfrag8*)(A1l + kA);

    for (int ks = 0; ks < 4; ks++) {
        // 1-deep prefetch of next K-slice A fragments (hides HBM/L2 latency under MFMAs)
        bfrag8 nh0 = ah0, nl0 = al0, nh1 = ah1, nl1 = al1;
        if (ks < 3) {
            int kn = (ks + 1) * 32 + kA;
            nh0 = *(const bfrag8*)(A0h + kn);
            nl0 = *(const bfrag8*)(A0l + kn);
            nh1 = *(const bfrag8*)(A1h + kn);
            nl1 = *(const bfrag8*)(A1l + kn);
        }
        int k0 = ks * 32 + kA;
#pragma unroll
        for (int ct = 0; ct < 16; ct++) {
            int wb = (ct * 16 + m16) * WPITCH + k0;
            bfrag8 bh = *(const bfrag8*)(Bhs + wb);
            bfrag8 bl = *(const bfrag8*)(Bls + wb);
            acc[0][ct] = __builtin_amdgcn_mfma_f32_16x16x32_bf16(ah0, bh, acc[0][ct], 0, 0, 0);
            acc[0][ct] = __builtin_amdgcn_mfma_f32_16x16x32_bf16(al0, bh, acc[0][ct], 0, 0, 0);
            acc[0][ct] = __builtin_amdgcn_mfma_f32_16x16x32_bf16(ah0, bl, acc[0][ct], 0, 0, 0);
            acc[1][ct] = __builtin_amdgcn_mfma_f32_16x16x32_bf16(ah1, bh, acc[1][ct], 0, 0, 0);
            acc[1][ct] = __builtin_amdgcn_mfma_f32_16x16x32_bf16(al1, bh, acc[1][ct], 0, 0, 0);
            acc[1][ct] = __builtin_amdgcn_mfma_f32_16x16x32_bf16(ah1, bl, acc[1][ct], 0, 0, 0);
        }
        ah0 = nh0; al0 = nl0; ah1 = nh1; al1 = nl1;
    }

    float bv[16], av[16];
    float pb2 = 0.0f;
#pragma unroll
    for (int ct = 0; ct < 16; ct++) {
        bv[ct] = bvec[ct * 16 + m16];
        av[ct] = attn[ct * 16 + m16];
        pb2 += bv[ct] * bv[ct];
    }
#pragma unroll
    for (int off = 1; off < 16; off <<= 1) pb2 += __shfl_xor(pb2, off, 64);

#pragma unroll
    for (int p = 0; p < 2; p++) {
        float pm2[4] = {0, 0, 0, 0}, pdb[4] = {0, 0, 0, 0};
#pragma unroll
        for (int ct = 0; ct < 16; ct++)
#pragma unroll
            for (int r = 0; r < 4; r++) {
                float v = acc[p][ct][r];
                pm2[r] += v * v;
                pdb[r] += v * bv[ct];
            }
#pragma unroll
        for (int off = 1; off < 16; off <<= 1)
#pragma unroll
            for (int r = 0; r < 4; r++) {
                pm2[r] += __shfl_xor(pm2[r], off, 64);
                pdb[r] += __shfl_xor(pdb[r], off, 64);
            }
#pragma unroll
        for (int r = 0; r < 4; r++) {
            int row_o = rowbase + p * 16 + kg * 4 + r;
            bool ok = row_o < M;
            float g = ok ? tnode[base + row_o] : 1.0f;
            float mxn = sqrtf(fmaxf(pm2[r], 1e-30f));
            float sv = tanhf(mxn * g) / mxn;
            float xy = sv * pdb[r];
            float x2v = sv * sv * pm2[r];
            float Am = 1.0f + 2.0f * xy + pb2;
            float Bm = 1.0f - x2v;
            float iden = 1.0f / fmaxf(1.0f + 2.0f * xy + x2v * pb2, 1e-15f);
            float pf2 = 0.0f, pa0 = 0.0f, pa1 = 0.0f;
#pragma unroll
            for (int ct = 0; ct < 16; ct++) {
                float f = (Am * sv * acc[p][ct][r] + Bm * bv[ct]) * iden;
                acc[p][ct][r] = f;
                pf2 += f * f;
                if (ct < 8) pa0 += f * av[ct]; else pa1 += f * av[ct];
            }
#pragma unroll
            for (int off = 1; off < 16; off <<= 1) {
                pf2 += __shfl_xor(pf2, off, 64);
                pa0 += __shfl_xor(pa0, off, 64);
                pa1 += __shfl_xor(pa1, off, 64);
            }
            if (ok) {
                float* fr = feat + (size_t)(base + row_o) * 256;
#pragma unroll
                for (int ct = 0; ct < 16; ct++) fr[ct * 16 + m16] = acc[p][ct][r];
                if (m16 == 0) {
                    float nf = sqrtf(fmaxf(pf2, 1e-30f));
                    float cl = atanhf(fminf(nf, ACLIP)) / nf;
                    x2a[base + row_o] = pf2;
                    ca[base + row_o] = cl;
                    satt[(size_t)(base + row_o) * 2 + 0] = cl * pa0;
                    satt[(size_t)(base + row_o) * 2 + 1] = cl * pa1;
                }
            }
        }
    }
}

// ---------- stage 4+5 fused: per-dst distances + softmaxes + gather + expmap0 ----------
// CAPR=16: LDS ~18.5 KB -> ~8 blocks/CU. Scalar softmax phases: wave 0 only,
// lane-parallel shuffle reductions (no block barriers).
#define CAPR 16
#define CAPE 64
__global__ __launch_bounds__(256) void k_aggregate(
        const int* __restrict__ rowptr, const int* __restrict__ es,
        const float* __restrict__ x2a, const float* __restrict__ satt,
        const float* __restrict__ ca, const float* __restrict__ feat,
        float* __restrict__ invg, float* __restrict__ w0g, float* __restrict__ w1g,
        void* __restrict__ out, const int* __restrict__ flag, int n_dst) {
    __shared__ float red[4];
    __shared__ float yrow[256];
    __shared__ float inv_s[CAPE], w0_s[CAPE], w1_s[CAPE];
    __shared__ int sb_s[CAPE];
    __shared__ float cache[CAPR * 256];
    int d = blockIdx.x;
    int t = threadIdx.x;
    int w = t >> 6, lane = t & 63;
    int off0 = rowptr[d], off1 = rowptr[d + 1];
    int deg = off1 - off0;
    if (deg == 0) {
        if (*flag) ((float*)out)[(size_t)d * 256 + t] = 0.0f;
        else ((unsigned short*)out)[(size_t)d * 256 + t] = 0;
        return;
    }
    yrow[t] = feat[(size_t)d * 256 + t];
    float y2 = x2a[d];
    __syncthreads();

    // pass A: per-edge dot + distance (wave per edge, 4 at a time); cache rows
    int c = lane * 4;
    float4 yv = *(const float4*)(&yrow[c]);
    for (int b = 0; b < deg; b += 4) {
        int j = b + w;
        if (j < deg) {
            int i = off0 + j;
            int s = es[i];
            float4 xv = *(const float4*)(feat + (size_t)s * 256 + c);
            float pd = wred(xv.x * yv.x + xv.y * yv.y + xv.z * yv.z + xv.w * yv.w);
            if (j < CAPR) *(float4*)&cache[j * 256 + c] = xv;
            if (lane == 0) {
                float x2 = x2a[s];
                float A = 1.0f - 2.0f * pd + y2;
                float B = 1.0f - x2;
                float iden = 1.0f / fmaxf(1.0f - 2.0f * pd + x2 * y2, 1e-15f);
                float p2 = fmaxf(A * A * x2 - 2.0f * A * B * pd + B * B * y2, 0.0f);
                float nrm = sqrtf(fmaxf(p2, 1e-30f)) * iden;
                float dd = 2.0f * atanhf(fminf(nrm, ACLIP));
                float iv = 1.0f / (1e-15f + dd);
                if (j < CAPE) { inv_s[j] = iv; sb_s[j] = s; }
                else { invg[i] = iv; }
            }
        }
    }
    __syncthreads();

    // scalar phases: wave 0 only, shuffle reductions
    if (w == 0) {
        float sd0 = satt[(size_t)d * 2 + 0], sd1 = satt[(size_t)d * 2 + 1];
        float lm = -INFINITY;
        for (int j = lane; j < deg; j += 64)
            lm = fmaxf(lm, (j < CAPE) ? inv_s[j] : invg[off0 + j]);
        float m1 = wredmax(lm);
        float ls = 0.0f;
        for (int j = lane; j < deg; j += 64)
            ls += expf(((j < CAPE) ? inv_s[j] : invg[off0 + j]) - m1);
        float is1 = 1.0f / wred(ls);
        float lm0 = -INFINITY, lm1 = -INFINITY;
        for (int j = lane; j < deg; j += 64) {
            int s = (j < CAPE) ? sb_s[j] : es[off0 + j];
            float iv = (j < CAPE) ? inv_s[j] : invg[off0 + j];
            float dsm = expf(iv - m1) * is1;
            float e0 = (satt[(size_t)s * 2 + 0] + sd0) * dsm; e0 = (e0 > 0.0f) ? e0 : 0.2f * e0;
            float e1 = (satt[(size_t)s * 2 + 1] + sd1) * dsm; e1 = (e1 > 0.0f) ? e1 : 0.2f * e1;
            if (j < CAPE) { w0_s[j] = e0; w1_s[j] = e1; }
            else { w0g[off0 + j] = e0; w1g[off0 + j] = e1; }
            lm0 = fmaxf(lm0, e0); lm1 = fmaxf(lm1, e1);
        }
        float m20 = wredmax(lm0), m21 = wredmax(lm1);
        float l20 = 0.0f, l21 = 0.0f;
        for (int j = lane; j < deg; j += 64) {
            float e0 = (j < CAPE) ? w0_s[j] : w0g[off0 + j];
            float e1 = (j < CAPE) ? w1_s[j] : w1g[off0 + j];
            l20 += expf(e0 - m20); l21 += expf(e1 - m21);
        }
        float is20 = 1.0f / wred(l20), is21 = 1.0f / wred(l21);
        for (int j = lane; j < deg; j += 64) {
            int s = (j < CAPE) ? sb_s[j] : es[off0 + j];
            float cs = ca[s];
            if (j < CAPE) {
                w0_s[j] = expf(w0_s[j] - m20) * is20 * cs;
                w1_s[j] = expf(w1_s[j] - m21) * is21 * cs;
            } else {
                w0g[off0 + j] = expf(w0g[off0 + j] - m20) * is20 * cs;
                w1g[off0 + j] = expf(w1g[off0 + j] - m21) * is21 * cs;
            }
        }
    }
    __syncthreads();

    // pass C: weighted gather (rows from LDS cache, spill from L2-hot global)
    int col = t, h = t >> 7;
    float acc = 0.0f;
    for (int j = 0; j < deg; j++) {
        float wgt = (j < CAPE) ? (h ? w1_s[j] : w0_s[j])
                               : (h ? w1g[off0 + j] : w0g[off0 + j]);
        float x;
        if (j < CAPR) x = cache[j * 256 + col];
        else {
            int s = (j < CAPE) ? sb_s[j] : es[off0 + j];
            x = feat[(size_t)s * 256 + col];
        }
        acc += wgt * x;
    }
    float p2 = bsum(acc * acc, red);
    float n = sqrtf(fmaxf(p2, 1e-30f));
    float sc = tanhf(n) / n;
    float o = acc * sc;
    if (*flag) ((float*)out)[(size_t)d * 256 + col] = o;
    else ((unsigned short*)out)[(size_t)d * 256 + col] = f2bf(o);
}

// ---------- host ----------
extern "C" void kernel_launch(void* const* d_in, const int* in_sizes, int n_in,
                              void* d_out, int out_size, void* d_ws, size_t ws_size,
                              hipStream_t stream) {
    const void* hyper  = d_in[0];
    const void* dt     = d_in[1];
    const void* time_w = d_in[2];
    const void* time_b = d_in[3];
    const void* w_src  = d_in[4];
    const void* b_src  = d_in[5];
    const void* w_dst  = d_in[6];
    const void* b_dst  = d_in[7];
    const void* attn   = d_in[8];
    const int* src_idx = (const int*)d_in[9];
    const int* dst_idx = (const int*)d_in[10];

    const int DIMN = 128, HD = 256;
    int n_edge  = in_sizes[1];
    int n_total = in_sizes[0] / DIMN;
    int n_dst   = n_total - n_edge;

    float* ws = (float*)d_ws;
    size_t off = 0;
    auto alloc = [&](size_t n) { float* p = ws + off; off += n; return p; };
    float* p_tw    = alloc(DIMN);
    float* p_tb    = alloc(DIMN);
    float* p_bsrc  = alloc(HD);
    float* p_bdst  = alloc(HD);
    float* p_attn  = alloc(HD);
    int*   p_flag  = (int*)alloc(4);
    unsigned short* p_whs = (unsigned short*)alloc((size_t)HD * DIMN / 2);
    unsigned short* p_wls = (unsigned short*)alloc((size_t)HD * DIMN / 2);
    unsigned short* p_whd = (unsigned short*)alloc((size_t)HD * DIMN / 2);
    unsigned short* p_wld = (unsigned short*)alloc((size_t)HD * DIMN / 2);
    unsigned short* p_ah = (unsigned short*)alloc((size_t)n_total * DIMN / 2);
    unsigned short* p_al = (unsigned short*)alloc((size_t)n_total * DIMN / 2);
    int* p_deg    = (int*)alloc(n_dst);
    int* p_rowptr = (int*)alloc(n_dst + 1);
    int* p_cursor = (int*)alloc(n_dst);
    int* p_es     = (int*)alloc(n_edge);
    float* p_inv  = alloc(n_edge);
    float* p_w0   = alloc(n_edge);
    float* p_w1   = alloc(n_edge);
    float* p_feat  = alloc((size_t)n_total * HD);
    float* p_tnode = alloc(n_total);
    float* p_call  = alloc(n_total);
    float* p_x2    = alloc(n_total);
    float* p_satt  = alloc((size_t)n_total * 2);
    (void)ws_size;

    const int TB = 256;
    auto cdiv = [](int a, int b) { return (a + b - 1) / b; };

    // raise dynamic-LDS cap for the GEMM kernel once (host-side attr, graph-safe)
    static bool lds_cfg = false;
    if (!lds_cfg) {
        hipFuncSetAttribute(reinterpret_cast<const void*>(k_gemm_ep),
                            hipFuncAttributeMaxDynamicSharedMemorySize, GEMM_LDS);
        lds_cfg = true;
    }

    k_detect<<<1, TB, 0, stream>>>((const unsigned short*)hyper, p_flag);

    k_params<<<cdiv(HD * DIMN, TB), TB, 0, stream>>>(
        w_src, w_dst, b_src, b_dst, attn, time_w, time_b,
        p_whs, p_wls, p_whd, p_wld, p_bsrc, p_bdst, p_attn, p_tw, p_tb,
        p_flag, HD * DIMN);

    k_fill<<<cdiv(n_dst, TB), TB, 0, stream>>>((unsigned*)p_deg, 0u, n_dst);
    k_hist<<<cdiv(n_edge, TB), TB, 0, stream>>>(dst_idx, p_deg, n_edge);
    k_scan<<<1, 1024, 0, stream>>>(p_deg, p_rowptr, p_cursor, n_dst);
    k_scatter_edges<<<cdiv(n_edge, TB), TB, 0, stream>>>(src_idx, dst_idx, p_cursor,
                                                         p_es, n_edge);

    k_node_prep<<<cdiv(n_total, 4), TB, 0, stream>>>(hyper, dt, p_tw, p_tb,
                                                     p_ah, p_al, p_tnode, p_flag,
                                                     n_dst, n_total);

    k_gemm_ep<<<cdiv(n_dst, 256), 512, GEMM_LDS, stream>>>(p_ah, p_al, p_whd, p_wld,
                                                           p_bdst, p_attn, p_tnode,
                                                           p_feat, p_x2, p_call, p_satt,
                                                           0, n_dst);
    k_gemm_ep<<<cdiv(n_edge, 256), 512, GEMM_LDS, stream>>>(p_ah + (size_t)n_dst * DIMN,
                                                            p_al + (size_t)n_dst * DIMN,
                                                            p_whs, p_wls,
                                                            p_bsrc, p_attn, p_tnode,
                                                            p_feat, p_x2, p_call, p_satt,
                                                            n_dst, n_edge);

    k_aggregate<<<n_dst, TB, 0, stream>>>(p_rowptr, p_es, p_x2, p_satt, p_call,
                                          p_feat, p_inv, p_w0, p_w1,
                                          d_out, p_flag, n_dst);
}

// Round 2
// 507.947 us; speedup vs baseline: 1.3785x; 1.1711x over previous
//
#include <hip/hip_runtime.h>
#include <hip/hip_bf16.h>
#include <math.h>

typedef __attribute__((ext_vector_type(8))) short bfrag8;
typedef __attribute__((ext_vector_type(4))) float ffrag4;

// ---------- helpers ----------
__device__ inline float bf2f(unsigned short h) { return __uint_as_float(((unsigned)h) << 16); }
__device__ inline unsigned short f2bf(float f) {
    unsigned u = __float_as_uint(f);
    unsigned r = (u + 0x7FFFu + ((u >> 16) & 1u)) >> 16;
    return (unsigned short)r;
}
__device__ inline float wred(float v) {
    v += __shfl_xor(v, 1, 64);
    v += __shfl_xor(v, 2, 64);
    v += __shfl_xor(v, 4, 64);
    v += __shfl_xor(v, 8, 64);
    v += __shfl_xor(v, 16, 64);
    v += __shfl_xor(v, 32, 64);
    return v;
}
__device__ inline float wredmax(float v) {
    v = fmaxf(v, __shfl_xor(v, 1, 64));
    v = fmaxf(v, __shfl_xor(v, 2, 64));
    v = fmaxf(v, __shfl_xor(v, 4, 64));
    v = fmaxf(v, __shfl_xor(v, 8, 64));
    v = fmaxf(v, __shfl_xor(v, 16, 64));
    v = fmaxf(v, __shfl_xor(v, 32, 64));
    return v;
}
__device__ inline float bsum(float v, float* red) {
    v = wred(v);
    if ((threadIdx.x & 63) == 0) red[threadIdx.x >> 6] = v;
    __syncthreads();
    float r = red[0] + red[1] + red[2] + red[3];
    __syncthreads();
    return r;
}

#define ACLIP (1.0f - 1e-7f)
#define ATANH_ACLIP 8.4056196f   // atanh(1 - 1e-7)

// ---------- fast math (native-instruction) ----------
__device__ inline float rcpf(float x) { return __builtin_amdgcn_rcpf(x); }
__device__ inline float fsqrtf(float x) { return __builtin_amdgcn_sqrtf(x); }
__device__ inline float fexp(float x) { return __expf(x); }
__device__ inline float flog(float x) { return __logf(x); }
// atanh(x)/x for 0 <= x <= ACLIP; accurate at small x (poly) and near 1 (log form)
__device__ inline float atanh_over_x(float x) {
    if (x < 0.125f) {
        float x2 = x * x;
        return 1.0f + x2 * (0.33333333f + x2 * 0.2f);
    }
    return 0.5f * flog((1.0f + x) * rcpf(1.0f - x)) * rcpf(x);
}
// tanh(x)/x for x >= 0; accurate at small x
__device__ inline float tanh_over_x(float x) {
    if (x < 0.125f) {
        float x2 = x * x;
        return 1.0f - x2 * (0.33333333f - x2 * 0.13333333f);
    }
    float e = fexp(-2.0f * x);
    return (1.0f - e) * rcpf((1.0f + e) * x);
}
// cos(x radians) via Cody-Waite reduction to revolutions + v_cos_f32.
// |x| <= ~1e4 here; reduction error ~1e-7 rev.
__device__ inline float fcosr(float x) {
    const float C  = 0.15915494309189535f;   // 1/(2pi)
    const float C1 = 0.1591796875f;          // 12-bit head
    const float C2 = -2.4744408e-5f;         // 1/(2pi) - C1
    float k = __builtin_rintf(x * C);
    float f = fmaf(x, C1, -k);
    f = fmaf(x, C2, f);
    return __builtin_amdgcn_cosf(f);
}

// ---------- dtype detection ----------
__global__ void k_detect(const unsigned short* __restrict__ hyper, int* __restrict__ flag) {
    __shared__ int total;
    int t = threadIdx.x;
    if (t == 0) total = 0;
    __syncthreads();
    int cnt = 0;
    for (int i = t * 8; i < t * 8 + 8; i++) {
        if ((i & 1) == 0) {
            unsigned e = ((unsigned)hyper[i] >> 7) & 0xFF;
            if (e >= 0xC0) cnt++;
        }
    }
    atomicAdd(&total, cnt);
    __syncthreads();
    if (t == 0) *flag = (total >= 32) ? 1 : 0;   // 1 = inputs are float32
}

// ---------- fused small-param conversion ----------
__device__ inline float ldin(const void* s, int i, int isf32) {
    return isf32 ? ((const float*)s)[i] : bf2f(((const unsigned short*)s)[i]);
}
__global__ void k_params(const void* __restrict__ w_src, const void* __restrict__ w_dst,
                         const void* __restrict__ b_src, const void* __restrict__ b_dst,
                         const void* __restrict__ attn, const void* __restrict__ time_w,
                         const void* __restrict__ time_b,
                         unsigned short* __restrict__ whs, unsigned short* __restrict__ wls,
                         unsigned short* __restrict__ whd, unsigned short* __restrict__ wld,
                         float* __restrict__ bsrc, float* __restrict__ bdst,
                         float* __restrict__ pattn, float* __restrict__ tw,
                         float* __restrict__ tb, const int* __restrict__ flag, int nw) {
    int i = blockIdx.x * blockDim.x + threadIdx.x;
    int isf32 = *flag;
    if (i < nw) {
        float x = ldin(w_src, i, isf32);
        unsigned short h = f2bf(x);
        whs[i] = h; wls[i] = f2bf(x - bf2f(h));
        float y = ldin(w_dst, i, isf32);
        unsigned short g = f2bf(y);
        whd[i] = g; wld[i] = f2bf(y - bf2f(g));
    }
    if (i < 256) {
        bsrc[i] = ldin(b_src, i, isf32);
        bdst[i] = ldin(b_dst, i, isf32);
        pattn[i] = ldin(attn, i, isf32);
    }
    if (i < 128) {
        tw[i] = ldin(time_w, i, isf32);
        tb[i] = ldin(time_b, i, isf32);
    }
}
__global__ void k_fill(unsigned* __restrict__ p, unsigned v, int n) {
    int i = blockIdx.x * blockDim.x + threadIdx.x;
    if (i < n) p[i] = v;
}

// ---------- CSR build ----------
__global__ void k_hist(const int* __restrict__ dst_idx, int* __restrict__ deg, int n_edge) {
    int i = blockIdx.x * blockDim.x + threadIdx.x;
    if (i < n_edge) atomicAdd(deg + dst_idx[i], 1);
}
__global__ __launch_bounds__(1024) void k_scan(const int* __restrict__ deg,
                                               int* __restrict__ rowptr,
                                               int* __restrict__ cursor, int n) {
    __shared__ int part[1024];
    int t = threadIdx.x;
    int chunk = (n + 1023) >> 10;
    int lo = t * chunk, hi = min(lo + chunk, n);
    int s = 0;
    for (int i = lo; i < hi; i++) s += deg[i];
    part[t] = s;
    __syncthreads();
    for (int dd = 1; dd < 1024; dd <<= 1) {
        int v = (t >= dd) ? part[t - dd] : 0;
        __syncthreads();
        part[t] += v;
        __syncthreads();
    }
    int base = (t == 0) ? 0 : part[t - 1];
    for (int i = lo; i < hi; i++) {
        rowptr[i] = base; cursor[i] = base;
        base += deg[i];
    }
    if (t == 0) rowptr[n] = part[1023];
}
__global__ void k_scatter_edges(const int* __restrict__ src_idx, const int* __restrict__ dst_idx,
                                int* __restrict__ cursor, int* __restrict__ es, int n_edge) {
    int i = blockIdx.x * blockDim.x + threadIdx.x;
    if (i >= n_edge) return;
    int slot = atomicAdd(cursor + dst_idx[i], 1);
    es[slot] = src_idx[i];
}

// ---------- stage 1: per-node prologue (wave per node) -> Ah/Al bf16 split ----------
__global__ void k_node_prep(const void* __restrict__ hyper_v,
                            const void* __restrict__ dt_v,
                            const float* __restrict__ tw, const float* __restrict__ tb,
                            unsigned short* __restrict__ Ah, unsigned short* __restrict__ Al,
                            float* __restrict__ tnode,
                            const int* __restrict__ flag, int n_dst, int n_total) {
    int wid  = (blockIdx.x * blockDim.x + threadIdx.x) >> 6;
    int lane = threadIdx.x & 63;
    if (wid >= n_total) return;
    int isf32 = *flag;
    float tval = 0.0f;
    if (wid >= n_dst) {
        int e = wid - n_dst;
        tval = isf32 ? ((const float*)dt_v)[e] : bf2f(((const unsigned short*)dt_v)[e]);
    }
    int j0 = lane * 2;
    float tf0 = fcosr(tval * tw[j0]     + tb[j0]);
    float tf1 = fcosr(tval * tw[j0 + 1] + tb[j0 + 1]);
    float h0, h1;
    if (isf32) {
        const float* hp = (const float*)hyper_v + (size_t)wid * 128 + j0;
        h0 = hp[0]; h1 = hp[1];
    } else {
        const unsigned short* hp = (const unsigned short*)hyper_v + (size_t)wid * 128 + j0;
        h0 = bf2f(hp[0]); h1 = bf2f(hp[1]);
    }
    float ptf2 = wred(tf0 * tf0 + tf1 * tf1);
    float ph2  = wred(h0 * h0 + h1 * h1);
    float pht  = wred(h0 * tf0 + h1 * tf1);
    float ntf = fsqrtf(fmaxf(ptf2, 1e-30f));
    float maxn = 1.0f - 0.004f;
    float sc = (ntf > maxn) ? (maxn * rcpf(ntf)) : 1.0f;
    float y2 = sc * sc * ptf2, xy = sc * pht, x2 = ph2;
    float A = 1.0f + 2.0f * xy + y2;
    float B = 1.0f - x2;
    float iden = rcpf(fmaxf(1.0f + 2.0f * xy + x2 * y2, 1e-15f));
    float s0 = (A * h0 + B * sc * tf0) * iden;
    float s1 = (A * h1 + B * sc * tf1) * iden;
    unsigned short h0s = f2bf(s0), h1s = f2bf(s1);
    unsigned short l0s = f2bf(s0 - bf2f(h0s)), l1s = f2bf(s1 - bf2f(h1s));
    *(ushort2*)(Ah + (size_t)wid * 128 + j0) = make_ushort2(h0s, h1s);
    *(ushort2*)(Al + (size_t)wid * 128 + j0) = make_ushort2(l0s, l1s);
    float ps2 = wred(s0 * s0 + s1 * s1);
    float xn = fsqrtf(fmaxf(ps2, 1e-30f));
    float g = (xn > ACLIP) ? (ATANH_ACLIP * rcpf(xn)) : atanh_over_x(xn);
    if (lane == 0) tnode[wid] = g;
}

// ---------- stage 2+3 fused: split-bf16 MFMA GEMM (32 rows/wave) + epilogue ----------
// B (Wh+Wl) staged in LDS once per 512-thread block (8 waves, 256 rows).
#define WPITCH 136
#define GEMM_LDS (256 * WPITCH * 2 * 2)   // 139264 B -> 1 block/CU
__global__ __launch_bounds__(512, 2) void k_gemm_ep(
        const unsigned short* __restrict__ Ah, const unsigned short* __restrict__ Al,
        const unsigned short* __restrict__ Wh, const unsigned short* __restrict__ Wl,
        const float* __restrict__ bvec, const float* __restrict__ attn,
        const float* __restrict__ tnode,
        float* __restrict__ feat, float* __restrict__ x2a, float* __restrict__ ca,
        float* __restrict__ satt, int base, int M) {
    extern __shared__ unsigned short smem[];
    unsigned short* Bhs = smem;                    // [256][WPITCH]
    unsigned short* Bls = smem + 256 * WPITCH;

    int t = threadIdx.x;
    for (int v = t; v < 4096; v += 512) {
        int e = v << 3;
        int row = e >> 7, col = e & 127;
        *(bfrag8*)(Bhs + row * WPITCH + col) = *(const bfrag8*)(Wh + e);
        *(bfrag8*)(Bls + row * WPITCH + col) = *(const bfrag8*)(Wl + e);
    }
    __syncthreads();

    int w = t >> 6, lane = t & 63;
    int m16 = lane & 15, kg = lane >> 4;
    int rowbase = (blockIdx.x * 8 + w) * 32;
    int ar0 = min(rowbase + m16, M - 1);
    int ar1 = min(rowbase + 16 + m16, M - 1);
    const unsigned short* A0h = Ah + (size_t)ar0 * 128;
    const unsigned short* A0l = Al + (size_t)ar0 * 128;
    const unsigned short* A1h = Ah + (size_t)ar1 * 128;
    const unsigned short* A1l = Al + (size_t)ar1 * 128;

    ffrag4 acc[2][16];
#pragma unroll
    for (int p = 0; p < 2; p++)
#pragma unroll
        for (int ct = 0; ct < 16; ct++) acc[p][ct] = (ffrag4){0.0f, 0.0f, 0.0f, 0.0f};

    int kA = kg * 8;
    bfrag8 ah0 = *(const bfrag8*)(A0h + kA);
    bfrag8 al0 = *(const bfrag8*)(A0l + kA);
    bfrag8 ah1 = *(const bfrag8*)(A1h + kA);
    bfrag8 al1 = *(const bfrag8*)(A1l + kA);

    for (int ks = 0; ks < 4; ks++) {
        bfrag8 nh0 = ah0, nl0 = al0, nh1 = ah1, nl1 = al1;
        if (ks < 3) {
            int kn = (ks + 1) * 32 + kA;
            nh0 = *(const bfrag8*)(A0h + kn);
            nl0 = *(const bfrag8*)(A0l + kn);
            nh1 = *(const bfrag8*)(A1h + kn);
            nl1 = *(const bfrag8*)(A1l + kn);
        }
        int k0 = ks * 32 + kA;
#pragma unroll
        for (int ct = 0; ct < 16; ct++) {
            int wb = (ct * 16 + m16) * WPITCH + k0;
            bfrag8 bh = *(const bfrag8*)(Bhs + wb);
            bfrag8 bl = *(const bfrag8*)(Bls + wb);
            acc[0][ct] = __builtin_amdgcn_mfma_f32_16x16x32_bf16(ah0, bh, acc[0][ct], 0, 0, 0);
            acc[0][ct] = __builtin_amdgcn_mfma_f32_16x16x32_bf16(al0, bh, acc[0][ct], 0, 0, 0);
            acc[0][ct] = __builtin_amdgcn_mfma_f32_16x16x32_bf16(ah0, bl, acc[0][ct], 0, 0, 0);
            acc[1][ct] = __builtin_amdgcn_mfma_f32_16x16x32_bf16(ah1, bh, acc[1][ct], 0, 0, 0);
            acc[1][ct] = __builtin_amdgcn_mfma_f32_16x16x32_bf16(al1, bh, acc[1][ct], 0, 0, 0);
            acc[1][ct] = __builtin_amdgcn_mfma_f32_16x16x32_bf16(ah1, bl, acc[1][ct], 0, 0, 0);
        }
        ah0 = nh0; al0 = nl0; ah1 = nh1; al1 = nl1;
    }

    float bv[16], av[16];
    float pb2 = 0.0f;
#pragma unroll
    for (int ct = 0; ct < 16; ct++) {
        bv[ct] = bvec[ct * 16 + m16];
        av[ct] = attn[ct * 16 + m16];
        pb2 += bv[ct] * bv[ct];
    }
#pragma unroll
    for (int off = 1; off < 16; off <<= 1) pb2 += __shfl_xor(pb2, off, 64);

#pragma unroll
    for (int p = 0; p < 2; p++) {
        float pm2[4] = {0, 0, 0, 0}, pdb[4] = {0, 0, 0, 0};
#pragma unroll
        for (int ct = 0; ct < 16; ct++)
#pragma unroll
            for (int r = 0; r < 4; r++) {
                float v = acc[p][ct][r];
                pm2[r] += v * v;
                pdb[r] += v * bv[ct];
            }
#pragma unroll
        for (int off = 1; off < 16; off <<= 1)
#pragma unroll
            for (int r = 0; r < 4; r++) {
                pm2[r] += __shfl_xor(pm2[r], off, 64);
                pdb[r] += __shfl_xor(pdb[r], off, 64);
            }
#pragma unroll
        for (int r = 0; r < 4; r++) {
            int row_o = rowbase + p * 16 + kg * 4 + r;
            bool ok = row_o < M;
            float g = ok ? tnode[base + row_o] : 1.0f;
            float mxn = fsqrtf(fmaxf(pm2[r], 1e-30f));
            float sv = g * tanh_over_x(mxn * g);
            float xy = sv * pdb[r];
            float x2v = sv * sv * pm2[r];
            float Am = 1.0f + 2.0f * xy + pb2;
            float Bm = 1.0f - x2v;
            float iden = rcpf(fmaxf(1.0f + 2.0f * xy + x2v * pb2, 1e-15f));
            float pf2 = 0.0f, pa0 = 0.0f, pa1 = 0.0f;
#pragma unroll
            for (int ct = 0; ct < 16; ct++) {
                float f = (Am * sv * acc[p][ct][r] + Bm * bv[ct]) * iden;
                acc[p][ct][r] = f;
                pf2 += f * f;
                if (ct < 8) pa0 += f * av[ct]; else pa1 += f * av[ct];
            }
#pragma unroll
            for (int off = 1; off < 16; off <<= 1) {
                pf2 += __shfl_xor(pf2, off, 64);
                pa0 += __shfl_xor(pa0, off, 64);
                pa1 += __shfl_xor(pa1, off, 64);
            }
            if (ok) {
                float* fr = feat + (size_t)(base + row_o) * 256;
#pragma unroll
                for (int ct = 0; ct < 16; ct++) fr[ct * 16 + m16] = acc[p][ct][r];
                if (m16 == 0) {
                    float nf = fsqrtf(fmaxf(pf2, 1e-30f));
                    float cl = (nf > ACLIP) ? (ATANH_ACLIP * rcpf(nf)) : atanh_over_x(nf);
                    x2a[base + row_o] = pf2;
                    ca[base + row_o] = cl;
                    satt[(size_t)(base + row_o) * 2 + 0] = cl * pa0;
                    satt[(size_t)(base + row_o) * 2 + 1] = cl * pa1;
                }
            }
        }
    }
}

// ---------- stage 4+5 fused: per-dst distances + softmaxes + gather + expmap0 ----------
// Pass A: 16 lanes per edge (4 edges/wave/iter) -> 4x MLP, 4-wide divergent tail.
// Pass B: register-resident single-iteration fast path for deg <= 64.
#define CAPR 16
#define CAPE 64
__global__ __launch_bounds__(256) void k_aggregate(
        const int* __restrict__ rowptr, const int* __restrict__ es,
        const float* __restrict__ x2a, const float* __restrict__ satt,
        const float* __restrict__ ca, const float* __restrict__ feat,
        float* __restrict__ invg, float* __restrict__ w0g, float* __restrict__ w1g,
        void* __restrict__ out, const int* __restrict__ flag, int n_dst) {
    __shared__ float red[4];
    __shared__ float yrow[256];
    __shared__ float inv_s[CAPE], w0_s[CAPE], w1_s[CAPE];
    __shared__ int sb_s[CAPE];
    __shared__ float cache[CAPR * 256];
    int d = blockIdx.x;
    int t = threadIdx.x;
    int w = t >> 6, lane = t & 63;
    int off0 = rowptr[d], off1 = rowptr[d + 1];
    int deg = off1 - off0;
    if (deg == 0) {
        if (*flag) ((float*)out)[(size_t)d * 256 + t] = 0.0f;
        else ((unsigned short*)out)[(size_t)d * 256 + t] = 0;
        return;
    }
    yrow[t] = feat[(size_t)d * 256 + t];
    float y2 = x2a[d];
    __syncthreads();

    // pass A: 16 lanes per edge; 16 edges per iteration across the 4 waves
    int g16 = lane >> 4, sub = lane & 15;
    int cb = sub * 16;
    float4 yv0 = *(const float4*)(&yrow[cb + 0]);
    float4 yv1 = *(const float4*)(&yrow[cb + 4]);
    float4 yv2 = *(const float4*)(&yrow[cb + 8]);
    float4 yv3 = *(const float4*)(&yrow[cb + 12]);
    for (int b = 0; b < deg; b += 16) {
        int j = b + w * 4 + g16;
        if (j < deg) {
            int i = off0 + j;
            int s = es[i];
            const float* xr = feat + (size_t)s * 256 + cb;
            float4 x0 = *(const float4*)(xr + 0);
            float4 x1 = *(const float4*)(xr + 4);
            float4 x2f = *(const float4*)(xr + 8);
            float4 x3 = *(const float4*)(xr + 12);
            float pd = x0.x * yv0.x + x0.y * yv0.y + x0.z * yv0.z + x0.w * yv0.w
                     + x1.x * yv1.x + x1.y * yv1.y + x1.z * yv1.z + x1.w * yv1.w
                     + x2f.x * yv2.x + x2f.y * yv2.y + x2f.z * yv2.z + x2f.w * yv2.w
                     + x3.x * yv3.x + x3.y * yv3.y + x3.z * yv3.z + x3.w * yv3.w;
            pd += __shfl_xor(pd, 1, 64);
            pd += __shfl_xor(pd, 2, 64);
            pd += __shfl_xor(pd, 4, 64);
            pd += __shfl_xor(pd, 8, 64);
            if (j < CAPR) {
                float* cr = &cache[j * 256 + cb];
                *(float4*)(cr + 0) = x0;
                *(float4*)(cr + 4) = x1;
                *(float4*)(cr + 8) = x2f;
                *(float4*)(cr + 12) = x3;
            }
            if (sub == 0) {
                float x2 = x2a[s];
                float A = 1.0f - 2.0f * pd + y2;
                float B = 1.0f - x2;
                float iden = rcpf(fmaxf(1.0f - 2.0f * pd + x2 * y2, 1e-15f));
                float p2 = fmaxf(A * A * x2 - 2.0f * A * B * pd + B * B * y2, 0.0f);
                float nrm = fsqrtf(fmaxf(p2, 1e-30f)) * iden;
                float xc = fminf(nrm, ACLIP);
                float dd = 2.0f * xc * atanh_over_x(xc);
                float iv = rcpf(1e-15f + dd);
                if (j < CAPE) { inv_s[j] = iv; sb_s[j] = s; }
                else { invg[i] = iv; }
            }
        }
    }
    __syncthreads();

    // softmax phases: wave 0 only
    if (w == 0) {
        float sd0 = satt[(size_t)d * 2 + 0], sd1 = satt[(size_t)d * 2 + 1];
        if (deg <= CAPE) {
            // register-resident: lane j owns edge j; single pass, no LDS round-trips
            int j = lane;
            bool act = j < deg;
            int s = act ? sb_s[j] : 0;
            float iv = act ? inv_s[j] : -INFINITY;
            float m1 = wredmax(iv);
            float z = fexp(iv - m1);          // exp(-inf)=0 for inactive lanes
            float is1 = rcpf(wred(z));
            float dsm = z * is1;
            float a0 = act ? satt[(size_t)s * 2 + 0] : 0.0f;
            float a1 = act ? satt[(size_t)s * 2 + 1] : 0.0f;
            float e0 = (a0 + sd0) * dsm; e0 = (e0 > 0.0f) ? e0 : 0.2f * e0;
            float e1 = (a1 + sd1) * dsm; e1 = (e1 > 0.0f) ? e1 : 0.2f * e1;
            float m20 = wredmax(act ? e0 : -INFINITY);
            float m21 = wredmax(act ? e1 : -INFINITY);
            float z0 = act ? fexp(e0 - m20) : 0.0f;
            float z1 = act ? fexp(e1 - m21) : 0.0f;
            float is20 = rcpf(wred(z0));
            float is21 = rcpf(wred(z1));
            if (act) {
                float cs = ca[s];
                w0_s[j] = z0 * is20 * cs;
                w1_s[j] = z1 * is21 * cs;
            }
        } else {
            float lm = -INFINITY;
            for (int j = lane; j < deg; j += 64)
                lm = fmaxf(lm, (j < CAPE) ? inv_s[j] : invg[off0 + j]);
            float m1 = wredmax(lm);
            float ls = 0.0f;
            for (int j = lane; j < deg; j += 64)
                ls += fexp(((j < CAPE) ? inv_s[j] : invg[off0 + j]) - m1);
            float is1 = rcpf(wred(ls));
            float lm0 = -INFINITY, lm1 = -INFINITY;
            for (int j = lane; j < deg; j += 64) {
                int s = (j < CAPE) ? sb_s[j] : es[off0 + j];
                float iv = (j < CAPE) ? inv_s[j] : invg[off0 + j];
                float dsm = fexp(iv - m1) * is1;
                float e0 = (satt[(size_t)s * 2 + 0] + sd0) * dsm; e0 = (e0 > 0.0f) ? e0 : 0.2f * e0;
                float e1 = (satt[(size_t)s * 2 + 1] + sd1) * dsm; e1 = (e1 > 0.0f) ? e1 : 0.2f * e1;
                if (j < CAPE) { w0_s[j] = e0; w1_s[j] = e1; }
                else { w0g[off0 + j] = e0; w1g[off0 + j] = e1; }
                lm0 = fmaxf(lm0, e0); lm1 = fmaxf(lm1, e1);
            }
            float m20 = wredmax(lm0), m21 = wredmax(lm1);
            float l20 = 0.0f, l21 = 0.0f;
            for (int j = lane; j < deg; j += 64) {
                float e0 = (j < CAPE) ? w0_s[j] : w0g[off0 + j];
                float e1 = (j < CAPE) ? w1_s[j] : w1g[off0 + j];
                l20 += fexp(e0 - m20); l21 += fexp(e1 - m21);
            }
            float is20 = rcpf(wred(l20)), is21 = rcpf(wred(l21));
            for (int j = lane; j < deg; j += 64) {
                int s = (j < CAPE) ? sb_s[j] : es[off0 + j];
                float cs = ca[s];
                if (j < CAPE) {
                    w0_s[j] = fexp(w0_s[j] - m20) * is20 * cs;
                    w1_s[j] = fexp(w1_s[j] - m21) * is21 * cs;
                } else {
                    w0g[off0 + j] = fexp(w0g[off0 + j] - m20) * is20 * cs;
                    w1g[off0 + j] = fexp(w1g[off0 + j] - m21) * is21 * cs;
                }
            }
        }
    }
    __syncthreads();

    // pass C: weighted gather (rows from LDS cache, spill from L2-hot global)
    int col = t, h = t >> 7;
    float acc = 0.0f;
    for (int j = 0; j < deg; j++) {
        float wgt = (j < CAPE) ? (h ? w1_s[j] : w0_s[j])
                               : (h ? w1g[off0 + j] : w0g[off0 + j]);
        float x;
        if (j < CAPR) x = cache[j * 256 + col];
        else {
            int s = (j < CAPE) ? sb_s[j] : es[off0 + j];
            x = feat[(size_t)s * 256 + col];
        }
        acc += wgt * x;
    }
    float p2 = bsum(acc * acc, red);
    float n = fsqrtf(fmaxf(p2, 1e-30f));
    float sc = tanh_over_x(n);
    float o = acc * sc;
    if (*flag) ((float*)out)[(size_t)d * 256 + col] = o;
    else ((unsigned short*)out)[(size_t)d * 256 + col] = f2bf(o);
}

// ---------- host ----------
extern "C" void kernel_launch(void* const* d_in, const int* in_sizes, int n_in,
                              void* d_out, int out_size, void* d_ws, size_t ws_size,
                              hipStream_t stream) {
    const void* hyper  = d_in[0];
    const void* dt     = d_in[1];
    const void* time_w = d_in[2];
    const void* time_b = d_in[3];
    const void* w_src  = d_in[4];
    const void* b_src  = d_in[5];
    const void* w_dst  = d_in[6];
    const void* b_dst  = d_in[7];
    const void* attn   = d_in[8];
    const int* src_idx = (const int*)d_in[9];
    const int* dst_idx = (const int*)d_in[10];

    const int DIMN = 128, HD = 256;
    int n_edge  = in_sizes[1];
    int n_total = in_sizes[0] / DIMN;
    int n_dst   = n_total - n_edge;

    float* ws = (float*)d_ws;
    size_t off = 0;
    auto alloc = [&](size_t n) { float* p = ws + off; off += n; return p; };
    float* p_tw    = alloc(DIMN);
    float* p_tb    = alloc(DIMN);
    float* p_bsrc  = alloc(HD);
    float* p_bdst  = alloc(HD);
    float* p_attn  = alloc(HD);
    int*   p_flag  = (int*)alloc(4);
    unsigned short* p_whs = (unsigned short*)alloc((size_t)HD * DIMN / 2);
    unsigned short* p_wls = (unsigned short*)alloc((size_t)HD * DIMN / 2);
    unsigned short* p_whd = (unsigned short*)alloc((size_t)HD * DIMN / 2);
    unsigned short* p_wld = (unsigned short*)alloc((size_t)HD * DIMN / 2);
    unsigned short* p_ah = (unsigned short*)alloc((size_t)n_total * DIMN / 2);
    unsigned short* p_al = (unsigned short*)alloc((size_t)n_total * DIMN / 2);
    int* p_deg    = (int*)alloc(n_dst);
    int* p_rowptr = (int*)alloc(n_dst + 1);
    int* p_cursor = (int*)alloc(n_dst);
    int* p_es     = (int*)alloc(n_edge);
    float* p_inv  = alloc(n_edge);
    float* p_w0   = alloc(n_edge);
    float* p_w1   = alloc(n_edge);
    float* p_feat  = alloc((size_t)n_total * HD);
    float* p_tnode = alloc(n_total);
    float* p_call  = alloc(n_total);
    float* p_x2    = alloc(n_total);
    float* p_satt  = alloc((size_t)n_total * 2);
    (void)ws_size;

    const int TB = 256;
    auto cdiv = [](int a, int b) { return (a + b - 1) / b; };

    static bool lds_cfg = false;
    if (!lds_cfg) {
        hipFuncSetAttribute(reinterpret_cast<const void*>(k_gemm_ep),
                            hipFuncAttributeMaxDynamicSharedMemorySize, GEMM_LDS);
        lds_cfg = true;
    }

    k_detect<<<1, TB, 0, stream>>>((const unsigned short*)hyper, p_flag);

    k_params<<<cdiv(HD * DIMN, TB), TB, 0, stream>>>(
        w_src, w_dst, b_src, b_dst, attn, time_w, time_b,
        p_whs, p_wls, p_whd, p_wld, p_bsrc, p_bdst, p_attn, p_tw, p_tb,
        p_flag, HD * DIMN);

    k_fill<<<cdiv(n_dst, TB), TB, 0, stream>>>((unsigned*)p_deg, 0u, n_dst);
    k_hist<<<cdiv(n_edge, TB), TB, 0, stream>>>(dst_idx, p_deg, n_edge);
    k_scan<<<1, 1024, 0, stream>>>(p_deg, p_rowptr, p_cursor, n_dst);
    k_scatter_edges<<<cdiv(n_edge, TB), TB, 0, stream>>>(src_idx, dst_idx, p_cursor,
                                                         p_es, n_edge);

    k_node_prep<<<cdiv(n_total, 4), TB, 0, stream>>>(hyper, dt, p_tw, p_tb,
                                                     p_ah, p_al, p_tnode, p_flag,
                                                     n_dst, n_total);

    k_gemm_ep<<<cdiv(n_dst, 256), 512, GEMM_LDS, stream>>>(p_ah, p_al, p_whd, p_wld,
                                                           p_bdst, p_attn, p_tnode,
                                                           p_feat, p_x2, p_call, p_satt,
                                                           0, n_dst);
    k_gemm_ep<<<cdiv(n_edge, 256), 512, GEMM_LDS, stream>>>(p_ah + (size_t)n_dst * DIMN,
                                                            p_al + (size_t)n_dst * DIMN,
                                                            p_whs, p_wls,
                                                            p_bsrc, p_attn, p_tnode,
                                                            p_feat, p_x2, p_call, p_satt,
                                                            n_dst, n_edge);

    k_aggregate<<<n_dst, TB, 0, stream>>>(p_rowptr, p_es, p_x2, p_satt, p_call,
                                          p_feat, p_inv, p_w0, p_w1,
                                          d_out, p_flag, n_dst);
}